// Round 2
// baseline (1261.843 us; speedup 1.0000x reference)
//
#include <hip/hip_runtime.h>

// NeighborCorrelator: out[b, 7i+j, h, w] =
//   inv_nx[b,h,w] * inv_ny[b,h+i-3,w+j-3] * sum_c x[b,c,h,w]*y[b,c,h+i-3,w+j-3]
// Normalizers factor out -> single fused pass, raw dots via bf16 MFMA.
//
// R2 changes vs R1 (478us, conflicts 5.3e7, occ 47%, WRITE 3.1x):
//  - staging: thread loads 8 consecutive channels at one pos, writes ONE b128
//    to LDS; lane map (cg=lane&3, pos=lane>>2) -> wave LDS writes cover a
//    contiguous 1024B span (conflict-free), global loads 4x64B dense segments.
//  - 512-thread blocks, TH=8 tile, 38.6KB LDS -> 4 blocks/CU.
//  - epilogue staged in LDS (aliases Yb) -> contiguous cooperative stores.

#define H_ 256
#define W_ 256
#define C_ 256
#define B_ 4
#define TH 8
#define TW 16
#define KCH 32             // channels per LDS chunk
#define NCHUNK (C_ / KCH)  // 8
#define HAL (TH + 6)       // 14
#define WAL (TW + 6)       // 22
#define YW 32              // padded w2 extent (2 MFMA N-tiles)
#define PLANE (H_ * W_)    // 65536
#define NYSLOT (HAL * WAL * 4)  // 1232 staging slots (pos x cgroup)

typedef __attribute__((ext_vector_type(8))) short short8;
typedef __attribute__((ext_vector_type(4))) float floatx4;
typedef __attribute__((ext_vector_type(4))) unsigned uintx4;

// pack two floats to bf16x2 (RNE), a -> low half (even channel)
__device__ __forceinline__ unsigned bfpair(float a, float b) {
  unsigned ua = __float_as_uint(a), ub = __float_as_uint(b);
  ua = (ua + 0x7FFFu + ((ua >> 16) & 1u)) >> 16;
  ub = (ub + 0x7FFFu + ((ub >> 16) & 1u)) & 0xFFFF0000u;
  return ub | ua;
}

__device__ __forceinline__ uintx4 pack8(const float f[8]) {
  uintx4 r;
  r.x = bfpair(f[0], f[1]);
  r.y = bfpair(f[2], f[3]);
  r.z = bfpair(f[4], f[5]);
  r.w = bfpair(f[6], f[7]);
  return r;
}

__global__ __launch_bounds__(512, 8) void ncorr(const float* __restrict__ x,
                                                const float* __restrict__ y,
                                                float* __restrict__ out) {
  // staging region (aliased by epilogue out-tile):
  //   Yb: short[14*32*32] = 28672 B   [hy][w2(32 padded)][c32]
  //   Xb: short[8*16*32]  =  8192 B   [h][w][c32]
  //   Ot: float[49*8*16]  = 25088 B   (aliases Yb)
  __shared__ __align__(16) char ldsbuf[HAL * YW * KCH * 2 + TH * TW * KCH * 2];
  __shared__ float sxl[TH * TW];    // sum x^2 per (h,w)
  __shared__ float syl[HAL * WAL];  // sum y^2 per (hy,wy)
  short* Yb = (short*)ldsbuf;
  short* Xb = (short*)(ldsbuf + HAL * YW * KCH * 2);
  float* Ot = (float*)ldsbuf;

  const int t = threadIdx.x;
  const int lane = t & 63;
  const int wv = t >> 6;  // wave id == local output h row (0..7)
  const int q = lane >> 4;
  const int lr = lane & 15;
  const int b = blockIdx.z;
  const int h0 = blockIdx.y * TH;
  const int w0 = blockIdx.x * TW;

  // ---- zero Yb pad columns w2 in [22,32) (never staged) ----
  for (int idx = t; idx < HAL * 10 * (KCH / 2); idx += 512) {
    int hy = idx / 160;           // 10 cols * 16 dwords
    int r = idx - hy * 160;
    int wy = 22 + (r >> 4);
    int dw = r & 15;
    ((unsigned*)Yb)[(hy * YW + wy) * (KCH / 2) + dw] = 0u;
  }
  if (t < TH * TW) sxl[t] = 0.f;
  if (t < HAL * WAL) syl[t] = 0.f;

  // ---- X staging slot: thread -> (cg = lane&3, w = lane>>2 (mod 16), h = wv)
  // loads 8 consecutive channels cg*8..cg*8+7 at one pos, writes 16B to LDS.
  const int xcg = lane & 3;
  const int xw = (lane >> 2) & 15;
  const int xgidx = ((b * C_ + xcg * 8) * H_ + (h0 + wv)) * W_ + (w0 + xw);
  const int xlds = (wv * TW + xw) * KCH + xcg * 8;  // short index, 16B aligned
  float sxacc = 0.f;

  // ---- Y staging slots: s = t + i*512, s < 1232; cg = s&3, p = s>>2
  int yidx[3], ylds[3], ypos[3];
  unsigned yval = 0, yok = 0;
  float syacc[3] = {0.f, 0.f, 0.f};
#pragma unroll
  for (int i = 0; i < 3; i++) {
    int s = t + i * 512;
    bool valid = s < NYSLOT;
    int cg = s & 3;
    int p = s >> 2;  // 0..307
    int hy = p / WAL;
    int wy = p - hy * WAL;
    int gy = h0 - 3 + hy;
    int gx = w0 - 3 + wy;
    bool inimg = valid && gy >= 0 && gy < H_ && gx >= 0 && gx < W_;
    if (valid) yval |= (1u << i);
    if (inimg) yok |= (1u << i);
    yidx[i] = ((b * C_ + cg * 8) * H_ + (inimg ? gy : 0)) * W_ + (inimg ? gx : 0);
    ylds[i] = (hy * YW + wy) * KCH + cg * 8;
    ypos[i] = p;
  }

  floatx4 acc[7][2];
#pragma unroll
  for (int i = 0; i < 7; i++) {
    acc[i][0] = (floatx4){0.f, 0.f, 0.f, 0.f};
    acc[i][1] = (floatx4){0.f, 0.f, 0.f, 0.f};
  }

  for (int ch = 0; ch < NCHUNK; ch++) {
    __syncthreads();  // protect LDS from previous iteration's readers
    const int coff = ch * (KCH * PLANE);
    // stage X (always in-image)
    {
      const float* p = x + xgidx + coff;
      float f[8];
#pragma unroll
      for (int k = 0; k < 8; k++) f[k] = p[k * PLANE];
#pragma unroll
      for (int k = 0; k < 8; k++) sxacc += f[k] * f[k];
      *(uintx4*)&Xb[xlds] = pack8(f);
    }
    // stage Y halo (image-OOB -> 0)
#pragma unroll
    for (int i = 0; i < 3; i++) {
      if (!((yval >> i) & 1)) continue;
      float f[8] = {0.f, 0.f, 0.f, 0.f, 0.f, 0.f, 0.f, 0.f};
      if ((yok >> i) & 1) {
        const float* p = y + yidx[i] + coff;
#pragma unroll
        for (int k = 0; k < 8; k++) f[k] = p[k * PLANE];
      }
#pragma unroll
      for (int k = 0; k < 8; k++) syacc[i] += f[k] * f[k];
      *(uintx4*)&Yb[ylds[i]] = pack8(f);
    }
    __syncthreads();
    // compute: wave wv -> output row h0+wv
    short8 A = *(const short8*)&Xb[(wv * TW + lr) * KCH + q * 8];
#pragma unroll
    for (int i = 0; i < 7; i++) {
#pragma unroll
      for (int nt = 0; nt < 2; nt++) {
        short8 Bf = *(const short8*)&Yb[((wv + i) * YW + nt * 16 + lr) * KCH + q * 8];
        acc[i][nt] = __builtin_amdgcn_mfma_f32_16x16x32_bf16(A, Bf, acc[i][nt], 0, 0, 0);
      }
    }
  }

  // ---- reduce norms (4-way contention per pos) ----
  __syncthreads();
  atomicAdd(&sxl[wv * TW + xw], sxacc);
#pragma unroll
  for (int i = 0; i < 3; i++)
    if ((yval >> i) & 1) atomicAdd(&syl[ypos[i]], syacc[i]);
  __syncthreads();
  if (t < TH * TW) sxl[t] = 1.f / fmaxf(sqrtf(sxl[t]), 1e-12f);
  if (t < HAL * WAL) syl[t] = 1.f / fmaxf(sqrtf(syl[t]), 1e-12f);
  __syncthreads();

  // ---- epilogue: C/D layout col(n)=lr(+16*nt), row(m)=q*4+r; stage to LDS
  // (Ot aliases Yb -- all MFMA reads of Yb completed before the barrier above)
#pragma unroll
  for (int i = 0; i < 7; i++) {
#pragma unroll
    for (int nt = 0; nt < 2; nt++) {
      const int n = nt * 16 + lr;  // w2 window index
#pragma unroll
      for (int r = 0; r < 4; r++) {
        const int m = q * 4 + r;  // output w within tile
        const int j = n - m;      // kernel w-offset
        if (j >= 0 && j < 7) {
          Ot[(7 * i + j) * (TH * TW) + wv * TW + m] =
              acc[i][nt][r] * sxl[wv * TW + m] * syl[(wv + i) * WAL + n];
        }
      }
    }
  }
  __syncthreads();
  // cooperative contiguous store: 6272 floats
  for (int idx = t; idx < 49 * TH * TW; idx += 512) {
    int p = idx >> 7;  // plane 0..48
    int rem = idx & 127;
    int hh = rem >> 4;
    int ww = rem & 15;
    out[((b * 49 + p) * H_ + (h0 + hh)) * W_ + (w0 + ww)] = Ot[idx];
  }
}

extern "C" void kernel_launch(void* const* d_in, const int* in_sizes, int n_in,
                              void* d_out, int out_size, void* d_ws, size_t ws_size,
                              hipStream_t stream) {
  const float* x = (const float*)d_in[0];
  const float* y = (const float*)d_in[1];
  float* out = (float*)d_out;
  dim3 grid(W_ / TW, H_ / TH, B_);
  ncorr<<<grid, 512, 0, stream>>>(x, y, out);
}